// Round 1
// baseline (2359.535 us; speedup 1.0000x reference)
//
#include <hip/hip_runtime.h>
#include <math.h>

// Problem constants (hard-coded from setup_inputs)
#define B_N 4
#define S_N 2048
#define D_N 1024
#define H_N 16
#define HD_N 64
#define M_N (B_N * S_N)   // 8192

// LDS swizzle for [64][64] fp32 tiles: 16B-group index g of row r stored at g ^ ((r>>2)&15).
// Makes row-reads (broadcast), column-ish reads, and staging writes all <=2-way bank aliased.
#define SWZ(r, g) ((g) ^ (((r) >> 2) & 15))

// ---------------------------------------------------------------------------
// Kernel 1: RoPE cos/sin table (S_N x 32)
// ---------------------------------------------------------------------------
__global__ __launch_bounds__(256)
void rope_table_kernel(float* __restrict__ cos_t, float* __restrict__ sin_t) {
    int idx = blockIdx.x * 256 + threadIdx.x;
    if (idx >= S_N * 32) return;
    int sp = idx >> 5;
    int p  = idx & 31;
    float inv = powf(10000.0f, -(float)p / 32.0f);
    float ang = (float)sp * inv;
    float s, c;
    sincosf(ang, &s, &c);   // precise libm version: table built once, cost negligible
    cos_t[idx] = c;
    sin_t[idx] = s;
}

// ---------------------------------------------------------------------------
// Kernel 2: fused QKV GEMM  (x[8192x1024] @ W[1024x1024] + b), epilogue applies
// RoPE (Q,K) and scatters to [B,H,S,64] layout.
// grid = (M/64, 48); each n-tile of 64 == exactly one (matrix, head).
// ---------------------------------------------------------------------------
__global__ __launch_bounds__(256)
void qkv_gemm_kernel(const float* __restrict__ x,
                     const float* __restrict__ Wq, const float* __restrict__ bq,
                     const float* __restrict__ Wk, const float* __restrict__ bk,
                     const float* __restrict__ Wv, const float* __restrict__ bv,
                     const float* __restrict__ cos_t, const float* __restrict__ sin_t,
                     float* __restrict__ Qr, float* __restrict__ Kr, float* __restrict__ Vr)
{
    const int mt   = blockIdx.x;      // 0..127
    const int nt   = blockIdx.y;      // 0..47
    const int mat  = nt >> 4;         // 0=Q,1=K,2=V
    const int head = nt & 15;
    const float* __restrict__ Bw   = (mat == 0) ? Wq : (mat == 1) ? Wk : Wv;
    const float* __restrict__ bias = (mat == 0) ? bq : (mat == 1) ? bk : bv;
    float* __restrict__ Out        = (mat == 0) ? Qr : (mat == 1) ? Kr : Vr;

    __shared__ float As[64][32];
    __shared__ float Bs[32][64];

    const int tid = threadIdx.x;
    const int tx  = tid & 15;
    const int ty  = tid >> 4;
    const int m0  = mt * 64;
    const int n0  = head * 64;

    // staging indices
    const int ar = tid >> 3;          // 0..31 (two passes for 64 rows)
    const int ac = (tid & 7) * 4;
    const int br = tid >> 4;          // 0..15 (two passes for 32 rows)
    const int bc = (tid & 15) * 4;

    float acc[4][4] = {{0.f}};

    for (int k0 = 0; k0 < D_N; k0 += 32) {
        float4 a0 = *(const float4*)&x[(size_t)(m0 + ar) * D_N + k0 + ac];
        float4 a1 = *(const float4*)&x[(size_t)(m0 + 32 + ar) * D_N + k0 + ac];
        float4 b0 = *(const float4*)&Bw[(size_t)(k0 + br) * D_N + n0 + bc];
        float4 b1 = *(const float4*)&Bw[(size_t)(k0 + 16 + br) * D_N + n0 + bc];
        __syncthreads();
        *(float4*)&As[ar][ac]      = a0;
        *(float4*)&As[32 + ar][ac] = a1;
        *(float4*)&Bs[br][bc]      = b0;
        *(float4*)&Bs[16 + br][bc] = b1;
        __syncthreads();
        #pragma unroll
        for (int g = 0; g < 8; ++g) {
            float4 a4[4];
            #pragma unroll
            for (int i = 0; i < 4; ++i)
                a4[i] = *(const float4*)&As[ty * 4 + i][g * 4];
            #pragma unroll
            for (int j = 0; j < 4; ++j) {
                float4 b4 = *(const float4*)&Bs[g * 4 + j][tx * 4];
                #pragma unroll
                for (int i = 0; i < 4; ++i) {
                    float a = (j == 0) ? a4[i].x : (j == 1) ? a4[i].y
                            : (j == 2) ? a4[i].z : a4[i].w;
                    acc[i][0] = fmaf(a, b4.x, acc[i][0]);
                    acc[i][1] = fmaf(a, b4.y, acc[i][1]);
                    acc[i][2] = fmaf(a, b4.z, acc[i][2]);
                    acc[i][3] = fmaf(a, b4.w, acc[i][3]);
                }
            }
        }
    }

    const float4 bias4 = *(const float4*)&bias[n0 + tx * 4];

    #pragma unroll
    for (int i = 0; i < 4; ++i) {
        int m  = m0 + ty * 4 + i;
        int bb = m >> 11;          // / S_N
        int sp = m & (S_N - 1);
        float v0 = acc[i][0] + bias4.x;
        float v1 = acc[i][1] + bias4.y;
        float v2 = acc[i][2] + bias4.z;
        float v3 = acc[i][3] + bias4.w;
        if (mat < 2) {             // RoPE for Q and K
            int p0 = tx * 2;
            float c0  = cos_t[sp * 32 + p0],     sn0 = sin_t[sp * 32 + p0];
            float c1  = cos_t[sp * 32 + p0 + 1], sn1 = sin_t[sp * 32 + p0 + 1];
            float a0 = v0, b0v = v1, a1 = v2, b1v = v3;
            v0 = a0 * c0 - b0v * sn0;
            v1 = a0 * sn0 + b0v * c0;
            v2 = a1 * c1 - b1v * sn1;
            v3 = a1 * sn1 + b1v * c1;
        }
        *(float4*)&Out[(((size_t)(bb * H_N + head)) * S_N + sp) * HD_N + tx * 4] =
            make_float4(v0, v1, v2, v3);
    }
}

// ---------------------------------------------------------------------------
// Kernel 3: flash attention, fp32. One block = one (b,h) x 64 query rows.
// grid = (S/64, H, B), 256 threads (16x16), 4x4 micro-tiles.
// ---------------------------------------------------------------------------
__global__ __launch_bounds__(256)
void attn_kernel(const float* __restrict__ Qr, const float* __restrict__ Kr,
                 const float* __restrict__ Vr, float* __restrict__ O)
{
    __shared__ float Qs[64 * 64];
    __shared__ float Ks[64 * 64];
    __shared__ float Vs[64 * 64];
    __shared__ float Ps[64 * 64];

    const int qt = blockIdx.x;   // 0..31
    const int h  = blockIdx.y;
    const int b  = blockIdx.z;
    const size_t base = (size_t)(b * H_N + h) * S_N * HD_N;
    const float* __restrict__ Qp = Qr + base + (size_t)qt * 64 * HD_N;
    const float* __restrict__ Kp = Kr + base;
    const float* __restrict__ Vp = Vr + base;

    const int tid = threadIdx.x;
    const int tx  = tid & 15;
    const int ty  = tid >> 4;
    const int sr  = tid >> 4;    // staging row within 16-row pass
    const int sg  = tid & 15;    // staging 16B-group

    // stage Q once (swizzled)
    #pragma unroll
    for (int p = 0; p < 4; ++p) {
        int r = p * 16 + sr;
        float4 v = *(const float4*)&Qp[r * HD_N + sg * 4];
        *(float4*)&Qs[r * 64 + 4 * SWZ(r, sg)] = v;
    }

    float acc[4][4] = {{0.f}};
    float m_r[4], l_r[4];
    #pragma unroll
    for (int i = 0; i < 4; ++i) { m_r[i] = -1e30f; l_r[i] = 0.f; }

    const float scale = 0.125f;   // 1/sqrt(64)

    for (int kt = 0; kt < S_N / 64; ++kt) {
        __syncthreads();   // prior PV readers done before K/V overwrite (also covers Q stage)
        #pragma unroll
        for (int p = 0; p < 4; ++p) {
            int r = p * 16 + sr;
            float4 kv = *(const float4*)&Kp[(size_t)(kt * 64 + r) * HD_N + sg * 4];
            float4 vv = *(const float4*)&Vp[(size_t)(kt * 64 + r) * HD_N + sg * 4];
            *(float4*)&Ks[r * 64 + 4 * SWZ(r, sg)] = kv;
            *(float4*)&Vs[r * 64 + 4 * SWZ(r, sg)] = vv;
        }
        __syncthreads();

        // S = Q K^T  (4x4 scores per thread)
        float s[4][4] = {{0.f}};
        #pragma unroll
        for (int g = 0; g < 16; ++g) {
            float4 q4[4], k4[4];
            #pragma unroll
            for (int i = 0; i < 4; ++i) {
                int qr = ty * 4 + i;
                q4[i] = *(const float4*)&Qs[qr * 64 + 4 * SWZ(qr, g)];
            }
            #pragma unroll
            for (int j = 0; j < 4; ++j) {
                int kc = tx * 4 + j;
                k4[j] = *(const float4*)&Ks[kc * 64 + 4 * SWZ(kc, g)];
            }
            #pragma unroll
            for (int i = 0; i < 4; ++i)
                #pragma unroll
                for (int j = 0; j < 4; ++j) {
                    s[i][j] = fmaf(q4[i].x, k4[j].x, s[i][j]);
                    s[i][j] = fmaf(q4[i].y, k4[j].y, s[i][j]);
                    s[i][j] = fmaf(q4[i].z, k4[j].z, s[i][j]);
                    s[i][j] = fmaf(q4[i].w, k4[j].w, s[i][j]);
                }
        }
        #pragma unroll
        for (int i = 0; i < 4; ++i)
            #pragma unroll
            for (int j = 0; j < 4; ++j) s[i][j] *= scale;

        // online softmax (rows spread over 16 lanes in tx)
        #pragma unroll
        for (int i = 0; i < 4; ++i) {
            float mx = fmaxf(fmaxf(s[i][0], s[i][1]), fmaxf(s[i][2], s[i][3]));
            #pragma unroll
            for (int w = 1; w < 16; w <<= 1)
                mx = fmaxf(mx, __shfl_xor(mx, w));
            float m_new = fmaxf(m_r[i], mx);
            float alpha = __expf(m_r[i] - m_new);
            float psum = 0.f;
            #pragma unroll
            for (int j = 0; j < 4; ++j) {
                s[i][j] = __expf(s[i][j] - m_new);
                psum += s[i][j];
            }
            #pragma unroll
            for (int w = 1; w < 16; w <<= 1)
                psum += __shfl_xor(psum, w);
            l_r[i] = l_r[i] * alpha + psum;
            m_r[i] = m_new;
            #pragma unroll
            for (int j = 0; j < 4; ++j) acc[i][j] *= alpha;
        }

        // write P tile
        #pragma unroll
        for (int i = 0; i < 4; ++i) {
            int qr = ty * 4 + i;
            *(float4*)&Ps[qr * 64 + 4 * SWZ(qr, tx)] =
                make_float4(s[i][0], s[i][1], s[i][2], s[i][3]);
        }
        __syncthreads();

        // O += P @ V   (thread covers q rows ty*4.., d cols tx*4..)
        #pragma unroll
        for (int g = 0; g < 16; ++g) {   // g = k-group
            float4 p4[4], v4[4];
            #pragma unroll
            for (int i = 0; i < 4; ++i) {
                int qr = ty * 4 + i;
                p4[i] = *(const float4*)&Ps[qr * 64 + 4 * SWZ(qr, g)];
            }
            #pragma unroll
            for (int j = 0; j < 4; ++j) {
                int kr = g * 4 + j;
                v4[j] = *(const float4*)&Vs[kr * 64 + 4 * SWZ(kr, tx)];
            }
            #pragma unroll
            for (int i = 0; i < 4; ++i)
                #pragma unroll
                for (int j = 0; j < 4; ++j) {
                    float p = (j == 0) ? p4[i].x : (j == 1) ? p4[i].y
                            : (j == 2) ? p4[i].z : p4[i].w;
                    acc[i][0] = fmaf(p, v4[j].x, acc[i][0]);
                    acc[i][1] = fmaf(p, v4[j].y, acc[i][1]);
                    acc[i][2] = fmaf(p, v4[j].z, acc[i][2]);
                    acc[i][3] = fmaf(p, v4[j].w, acc[i][3]);
                }
        }
    }

    // normalize + store to [B,S,A] layout
    #pragma unroll
    for (int i = 0; i < 4; ++i) {
        float inv = 1.0f / l_r[i];
        int qr = ty * 4 + i;
        size_t row = (size_t)b * S_N + qt * 64 + qr;
        *(float4*)&O[row * D_N + h * HD_N + tx * 4] =
            make_float4(acc[i][0] * inv, acc[i][1] * inv, acc[i][2] * inv, acc[i][3] * inv);
    }
}

// ---------------------------------------------------------------------------
// Kernel 4: output projection  C = O @ Wo + bo,  [8192x1024]@[1024x1024]
// grid = (M/64, 16)
// ---------------------------------------------------------------------------
__global__ __launch_bounds__(256)
void out_gemm_kernel(const float* __restrict__ A, const float* __restrict__ Bw,
                     const float* __restrict__ bias, float* __restrict__ C)
{
    const int mt = blockIdx.x;
    const int nt = blockIdx.y;

    __shared__ float As[64][32];
    __shared__ float Bs[32][64];

    const int tid = threadIdx.x;
    const int tx  = tid & 15;
    const int ty  = tid >> 4;
    const int m0  = mt * 64;
    const int n0  = nt * 64;

    const int ar = tid >> 3;
    const int ac = (tid & 7) * 4;
    const int br = tid >> 4;
    const int bc = (tid & 15) * 4;

    float acc[4][4] = {{0.f}};

    for (int k0 = 0; k0 < D_N; k0 += 32) {
        float4 a0 = *(const float4*)&A[(size_t)(m0 + ar) * D_N + k0 + ac];
        float4 a1 = *(const float4*)&A[(size_t)(m0 + 32 + ar) * D_N + k0 + ac];
        float4 b0 = *(const float4*)&Bw[(size_t)(k0 + br) * D_N + n0 + bc];
        float4 b1 = *(const float4*)&Bw[(size_t)(k0 + 16 + br) * D_N + n0 + bc];
        __syncthreads();
        *(float4*)&As[ar][ac]      = a0;
        *(float4*)&As[32 + ar][ac] = a1;
        *(float4*)&Bs[br][bc]      = b0;
        *(float4*)&Bs[16 + br][bc] = b1;
        __syncthreads();
        #pragma unroll
        for (int g = 0; g < 8; ++g) {
            float4 a4[4];
            #pragma unroll
            for (int i = 0; i < 4; ++i)
                a4[i] = *(const float4*)&As[ty * 4 + i][g * 4];
            #pragma unroll
            for (int j = 0; j < 4; ++j) {
                float4 b4 = *(const float4*)&Bs[g * 4 + j][tx * 4];
                #pragma unroll
                for (int i = 0; i < 4; ++i) {
                    float a = (j == 0) ? a4[i].x : (j == 1) ? a4[i].y
                            : (j == 2) ? a4[i].z : a4[i].w;
                    acc[i][0] = fmaf(a, b4.x, acc[i][0]);
                    acc[i][1] = fmaf(a, b4.y, acc[i][1]);
                    acc[i][2] = fmaf(a, b4.z, acc[i][2]);
                    acc[i][3] = fmaf(a, b4.w, acc[i][3]);
                }
            }
        }
    }

    const float4 bias4 = *(const float4*)&bias[n0 + tx * 4];
    #pragma unroll
    for (int i = 0; i < 4; ++i) {
        int m = m0 + ty * 4 + i;
        *(float4*)&C[(size_t)m * D_N + n0 + tx * 4] =
            make_float4(acc[i][0] + bias4.x, acc[i][1] + bias4.y,
                        acc[i][2] + bias4.z, acc[i][3] + bias4.w);
    }
}

// ---------------------------------------------------------------------------
extern "C" void kernel_launch(void* const* d_in, const int* in_sizes, int n_in,
                              void* d_out, int out_size, void* d_ws, size_t ws_size,
                              hipStream_t stream) {
    const float* x  = (const float*)d_in[0];
    const float* Wq = (const float*)d_in[1];
    const float* bq = (const float*)d_in[2];
    const float* Wk = (const float*)d_in[3];
    const float* bk = (const float*)d_in[4];
    const float* Wv = (const float*)d_in[5];
    const float* bv = (const float*)d_in[6];
    const float* Wo = (const float*)d_in[7];
    const float* bo = (const float*)d_in[8];
    float* out = (float*)d_out;

    float* ws    = (float*)d_ws;
    float* cos_t = ws;                       // 65536
    float* sin_t = cos_t + (size_t)S_N * 32; // 65536
    float* Qr    = sin_t + (size_t)S_N * 32; // 8388608 each
    float* Kr    = Qr + (size_t)M_N * 1024;
    float* Vr    = Kr + (size_t)M_N * 1024;
    float* Obuf  = Vr + (size_t)M_N * 1024;

    rope_table_kernel<<<256, 256, 0, stream>>>(cos_t, sin_t);

    dim3 g1(M_N / 64, 48);
    qkv_gemm_kernel<<<g1, 256, 0, stream>>>(x, Wq, bq, Wk, bk, Wv, bv,
                                            cos_t, sin_t, Qr, Kr, Vr);

    dim3 g2(S_N / 64, H_N, B_N);
    attn_kernel<<<g2, 256, 0, stream>>>(Qr, Kr, Vr, Obuf);

    dim3 g3(M_N / 64, 16);
    out_gemm_kernel<<<g3, 256, 0, stream>>>(Obuf, Wo, bo, out);
}

// Round 5
// 1572.866 us; speedup vs baseline: 1.5002x; 1.5002x over previous
//
#include <hip/hip_runtime.h>
#include <math.h>

// Problem constants (hard-coded from setup_inputs)
#define B_N 4
#define S_N 2048
#define D_N 1024
#define H_N 16
#define HD_N 64
#define M_N (B_N * S_N)   // 8192

typedef __attribute__((ext_vector_type(8))) short bf16x8;   // 8 bf16 = 4 VGPRs (MFMA A/B frag)
typedef __attribute__((ext_vector_type(4))) float f32x4;    // MFMA C/D frag

// bf16 round-to-nearest-even split helpers
static __device__ __forceinline__ unsigned short f2bf(float f) {
    unsigned int u = __float_as_uint(f);
    u += 0x7FFF + ((u >> 16) & 1);
    return (unsigned short)(u >> 16);
}
static __device__ __forceinline__ float bf2f(unsigned short h) {
    return __uint_as_float(((unsigned int)h) << 16);
}

// fp32 GEMM LDS swizzle (kernels 2/4): 16B-group g of row r stored at g ^ ((r>>2)&15)
#define SWZ(r, g) ((g) ^ (((r) >> 2) & 15))

// ---------------------------------------------------------------------------
// Kernel 1: RoPE cos/sin table (S_N x 32)
// ---------------------------------------------------------------------------
__global__ __launch_bounds__(256)
void rope_table_kernel(float* __restrict__ cos_t, float* __restrict__ sin_t) {
    int idx = blockIdx.x * 256 + threadIdx.x;
    if (idx >= S_N * 32) return;
    int sp = idx >> 5;
    int p  = idx & 31;
    float inv = powf(10000.0f, -(float)p / 32.0f);
    float ang = (float)sp * inv;
    float s, c;
    sincosf(ang, &s, &c);
    cos_t[idx] = c;
    sin_t[idx] = s;
}

// ---------------------------------------------------------------------------
// Kernel 2: fused QKV GEMM (fp32 core). Epilogue: bias + RoPE(Q,K) + Q*=1/8,
// then split into bf16 hi/lo and store:
//   Qh/Ql/Kh/Kl : [B,H,S,64]
//   Vth/Vtl     : [B,H,64,S]   (transposed, so attention PV B-frags are rows)
// grid = (M/64, 48)
// ---------------------------------------------------------------------------
__global__ __launch_bounds__(256)
void qkv_gemm_kernel(const float* __restrict__ x,
                     const float* __restrict__ Wq, const float* __restrict__ bq,
                     const float* __restrict__ Wk, const float* __restrict__ bk,
                     const float* __restrict__ Wv, const float* __restrict__ bv,
                     const float* __restrict__ cos_t, const float* __restrict__ sin_t,
                     unsigned short* __restrict__ Qh, unsigned short* __restrict__ Ql,
                     unsigned short* __restrict__ Kh, unsigned short* __restrict__ Kl,
                     unsigned short* __restrict__ Vth, unsigned short* __restrict__ Vtl)
{
    const int mt   = blockIdx.x;      // 0..127
    const int nt   = blockIdx.y;      // 0..47
    const int mat  = nt >> 4;         // 0=Q,1=K,2=V
    const int head = nt & 15;
    const float* __restrict__ Bw   = (mat == 0) ? Wq : (mat == 1) ? Wk : Wv;
    const float* __restrict__ bias = (mat == 0) ? bq : (mat == 1) ? bk : bv;

    __shared__ float As[64][32];
    __shared__ float Bs[32][64];

    const int tid = threadIdx.x;
    const int tx  = tid & 15;
    const int ty  = tid >> 4;
    const int m0  = mt * 64;
    const int n0  = head * 64;

    const int ar = tid >> 3;
    const int ac = (tid & 7) * 4;
    const int br = tid >> 4;
    const int bc = (tid & 15) * 4;

    float acc[4][4] = {{0.f}};

    for (int k0 = 0; k0 < D_N; k0 += 32) {
        float4 a0 = *(const float4*)&x[(size_t)(m0 + ar) * D_N + k0 + ac];
        float4 a1 = *(const float4*)&x[(size_t)(m0 + 32 + ar) * D_N + k0 + ac];
        float4 b0 = *(const float4*)&Bw[(size_t)(k0 + br) * D_N + n0 + bc];
        float4 b1 = *(const float4*)&Bw[(size_t)(k0 + 16 + br) * D_N + n0 + bc];
        __syncthreads();
        *(float4*)&As[ar][ac]      = a0;
        *(float4*)&As[32 + ar][ac] = a1;
        *(float4*)&Bs[br][bc]      = b0;
        *(float4*)&Bs[16 + br][bc] = b1;
        __syncthreads();
        #pragma unroll
        for (int g = 0; g < 8; ++g) {
            float4 a4[4];
            #pragma unroll
            for (int i = 0; i < 4; ++i)
                a4[i] = *(const float4*)&As[ty * 4 + i][g * 4];
            #pragma unroll
            for (int j = 0; j < 4; ++j) {
                float4 b4 = *(const float4*)&Bs[g * 4 + j][tx * 4];
                #pragma unroll
                for (int i = 0; i < 4; ++i) {
                    float a = (j == 0) ? a4[i].x : (j == 1) ? a4[i].y
                            : (j == 2) ? a4[i].z : a4[i].w;
                    acc[i][0] = fmaf(a, b4.x, acc[i][0]);
                    acc[i][1] = fmaf(a, b4.y, acc[i][1]);
                    acc[i][2] = fmaf(a, b4.z, acc[i][2]);
                    acc[i][3] = fmaf(a, b4.w, acc[i][3]);
                }
            }
        }
    }

    const float4 bias4 = *(const float4*)&bias[n0 + tx * 4];
    const int bb = m0 >> 11;          // batch (constant per block: 2048 % 64 == 0)

    if (mat == 2) {
        // V: transposed hi/lo store  Vt[(bb*16+head)*64 + d][s]
        const int sp0 = (m0 & (S_N - 1)) + ty * 4;
        #pragma unroll
        for (int j = 0; j < 4; ++j) {
            float bj = (j == 0) ? bias4.x : (j == 1) ? bias4.y
                     : (j == 2) ? bias4.z : bias4.w;
            float v0 = acc[0][j] + bj, v1 = acc[1][j] + bj;
            float v2 = acc[2][j] + bj, v3 = acc[3][j] + bj;
            ushort4 hi, lo;
            hi.x = f2bf(v0); lo.x = f2bf(v0 - bf2f(hi.x));
            hi.y = f2bf(v1); lo.y = f2bf(v1 - bf2f(hi.y));
            hi.z = f2bf(v2); lo.z = f2bf(v2 - bf2f(hi.z));
            hi.w = f2bf(v3); lo.w = f2bf(v3 - bf2f(hi.w));
            int d = tx * 4 + j;
            size_t base = ((size_t)(bb * H_N + head) * HD_N + d) * S_N + sp0;
            *(ushort4*)&Vth[base] = hi;
            *(ushort4*)&Vtl[base] = lo;
        }
    } else {
        unsigned short* __restrict__ Hi = (mat == 0) ? Qh : Kh;
        unsigned short* __restrict__ Lo = (mat == 0) ? Ql : Kl;
        #pragma unroll
        for (int i = 0; i < 4; ++i) {
            int m  = m0 + ty * 4 + i;
            int sp = m & (S_N - 1);
            float v0 = acc[i][0] + bias4.x;
            float v1 = acc[i][1] + bias4.y;
            float v2 = acc[i][2] + bias4.z;
            float v3 = acc[i][3] + bias4.w;
            // RoPE
            int p0 = tx * 2;
            float c0  = cos_t[sp * 32 + p0],     sn0 = sin_t[sp * 32 + p0];
            float c1  = cos_t[sp * 32 + p0 + 1], sn1 = sin_t[sp * 32 + p0 + 1];
            float a0 = v0, b0v = v1, a1 = v2, b1v = v3;
            v0 = a0 * c0 - b0v * sn0;
            v1 = a0 * sn0 + b0v * c0;
            v2 = a1 * c1 - b1v * sn1;
            v3 = a1 * sn1 + b1v * c1;
            if (mat == 0) {   // fold softmax scale 1/sqrt(64) into Q
                v0 *= 0.125f; v1 *= 0.125f; v2 *= 0.125f; v3 *= 0.125f;
            }
            ushort4 hi, lo;
            hi.x = f2bf(v0); lo.x = f2bf(v0 - bf2f(hi.x));
            hi.y = f2bf(v1); lo.y = f2bf(v1 - bf2f(hi.y));
            hi.z = f2bf(v2); lo.z = f2bf(v2 - bf2f(hi.z));
            hi.w = f2bf(v3); lo.w = f2bf(v3 - bf2f(hi.w));
            size_t base = ((size_t)(bb * H_N + head) * S_N + sp) * HD_N + tx * 4;
            *(ushort4*)&Hi[base] = hi;
            *(ushort4*)&Lo[base] = lo;
        }
    }
}

// ---------------------------------------------------------------------------
// Kernel 3: flash attention via split-bf16 MFMA (16x16x32, fp32 accumulate).
// One block = one (b,h) x 64 query rows; 4 waves, wave w owns q-rows w*16..+16.
// QK^T: Qh*Kh + Ql*Kh + Qh*Kl  (near-fp32 logits).  PV: P*(Vh+Vl), P in bf16.
// LDS tiles XOR-swizzled: ushort idx ^= (row&7)<<3 (16B slot granularity).
// grid = (S/64, H, B), 256 threads.
// ---------------------------------------------------------------------------
__global__ __launch_bounds__(256)
void attn_kernel(const unsigned short* __restrict__ Qh, const unsigned short* __restrict__ Ql,
                 const unsigned short* __restrict__ Kh, const unsigned short* __restrict__ Kl,
                 const unsigned short* __restrict__ Vh, const unsigned short* __restrict__ Vl,
                 float* __restrict__ O)
{
    __shared__ __align__(16) unsigned short KhS[4096];
    __shared__ __align__(16) unsigned short KlS[4096];
    __shared__ __align__(16) unsigned short VhS[4096];
    __shared__ __align__(16) unsigned short VlS[4096];
    __shared__ __align__(16) unsigned short Pb[4][1024];   // per-wave P tile [16][64]

    const int qt = blockIdx.x;
    const int h  = blockIdx.y;
    const int b  = blockIdx.z;
    const int bh = b * H_N + h;

    const int tid  = threadIdx.x;
    const int wave = tid >> 6;
    const int lane = tid & 63;
    const int l15  = lane & 15;
    const int lg   = lane >> 4;

    // Q fragments in registers (A-frag: row = l15, k = lg*8 + j, per 32-k step)
    const int qrow = qt * 64 + wave * 16 + l15;
    const size_t qbase = ((size_t)bh * S_N + qrow) * HD_N;
    bf16x8 qfh[2], qfl[2];
    qfh[0] = *(const bf16x8*)&Qh[qbase + lg * 8];
    qfh[1] = *(const bf16x8*)&Qh[qbase + 32 + lg * 8];
    qfl[0] = *(const bf16x8*)&Ql[qbase + lg * 8];
    qfl[1] = *(const bf16x8*)&Ql[qbase + 32 + lg * 8];

    f32x4 oacc[4];
    #pragma unroll
    for (int dt = 0; dt < 4; ++dt) oacc[dt] = (f32x4){0.f, 0.f, 0.f, 0.f};
    float m_r[4], l_r[4];
    #pragma unroll
    for (int r = 0; r < 4; ++r) { m_r[r] = -1e30f; l_r[r] = 0.f; }

    for (int kt = 0; kt < S_N / 64; ++kt) {
        __syncthreads();   // prior tile's K/V readers done before overwrite
        // stage K hi/lo + Vt hi/lo tiles (reg-staged, swizzled LDS writes)
        #pragma unroll
        for (int t = 0; t < 2; ++t) {
            int c   = tid + t * 256;        // 0..511 chunks of 16B
            int row = c >> 3;
            int sl  = c & 7;
            int li  = (row * 64 + sl * 8) ^ ((row & 7) << 3);
            size_t gk = ((size_t)bh * S_N + kt * 64 + row) * HD_N + sl * 8;
            size_t gv = ((size_t)bh * HD_N + row) * S_N + kt * 64 + sl * 8;
            bf16x8 vkh = *(const bf16x8*)&Kh[gk];
            bf16x8 vkl = *(const bf16x8*)&Kl[gk];
            bf16x8 vvh = *(const bf16x8*)&Vh[gv];
            bf16x8 vvl = *(const bf16x8*)&Vl[gv];
            *(bf16x8*)&KhS[li] = vkh;
            *(bf16x8*)&KlS[li] = vkl;
            *(bf16x8*)&VhS[li] = vvh;
            *(bf16x8*)&VlS[li] = vvl;
        }
        __syncthreads();

        // S = Q K^T : 4 kv n-tiles x 2 k-steps x 3 split terms
        f32x4 s[4];
        #pragma unroll
        for (int nt = 0; nt < 4; ++nt) s[nt] = (f32x4){0.f, 0.f, 0.f, 0.f};
        #pragma unroll
        for (int ks = 0; ks < 2; ++ks) {
            #pragma unroll
            for (int nt = 0; nt < 4; ++nt) {
                int row = nt * 16 + l15;
                int bi  = (row * 64 + ks * 32 + lg * 8) ^ ((row & 7) << 3);
                bf16x8 fkh = *(const bf16x8*)&KhS[bi];
                bf16x8 fkl = *(const bf16x8*)&KlS[bi];
                s[nt] = __builtin_amdgcn_mfma_f32_16x16x32_bf16(qfh[ks], fkh, s[nt], 0, 0, 0);
                s[nt] = __builtin_amdgcn_mfma_f32_16x16x32_bf16(qfl[ks], fkh, s[nt], 0, 0, 0);
                s[nt] = __builtin_amdgcn_mfma_f32_16x16x32_bf16(qfh[ks], fkl, s[nt], 0, 0, 0);
            }
        }

        // online softmax; C layout: row = lg*4 + r, col = nt*16 + l15
        #pragma unroll
        for (int r = 0; r < 4; ++r) {
            float mx = fmaxf(fmaxf(s[0][r], s[1][r]), fmaxf(s[2][r], s[3][r]));
            mx = fmaxf(mx, __shfl_xor(mx, 1));
            mx = fmaxf(mx, __shfl_xor(mx, 2));
            mx = fmaxf(mx, __shfl_xor(mx, 4));
            mx = fmaxf(mx, __shfl_xor(mx, 8));
            float mnew = fmaxf(m_r[r], mx);
            float al   = __expf(m_r[r] - mnew);
            float ps   = 0.f;
            #pragma unroll
            for (int nt = 0; nt < 4; ++nt) {
                float p = __expf(s[nt][r] - mnew);
                s[nt][r] = p;
                ps += p;
            }
            ps += __shfl_xor(ps, 1);
            ps += __shfl_xor(ps, 2);
            ps += __shfl_xor(ps, 4);
            ps += __shfl_xor(ps, 8);
            l_r[r] = l_r[r] * al + ps;
            m_r[r] = mnew;
            oacc[0][r] *= al; oacc[1][r] *= al;
            oacc[2][r] *= al; oacc[3][r] *= al;
            // scatter P row to this wave's private LDS tile (bf16)
            int prow = lg * 4 + r;
            #pragma unroll
            for (int nt = 0; nt < 4; ++nt) {
                Pb[wave][(prow * 64 + nt * 16 + l15) ^ ((prow & 7) << 3)] = f2bf(s[nt][r]);
            }
        }
        // wave-private buffer: LDS completion order only, no cross-wave barrier
        asm volatile("s_waitcnt lgkmcnt(0)" ::: "memory");

        // O += P @ V : A = P (from LDS), B = Vt rows
        #pragma unroll
        for (int ks = 0; ks < 2; ++ks) {
            int pi = (l15 * 64 + ks * 32 + lg * 8) ^ ((l15 & 7) << 3);
            bf16x8 pa = *(const bf16x8*)&Pb[wave][pi];
            #pragma unroll
            for (int dt = 0; dt < 4; ++dt) {
                int vrow = dt * 16 + l15;
                int vbi  = (vrow * 64 + ks * 32 + lg * 8) ^ ((vrow & 7) << 3);
                bf16x8 fvh = *(const bf16x8*)&VhS[vbi];
                bf16x8 fvl = *(const bf16x8*)&VlS[vbi];
                oacc[dt] = __builtin_amdgcn_mfma_f32_16x16x32_bf16(pa, fvh, oacc[dt], 0, 0, 0);
                oacc[dt] = __builtin_amdgcn_mfma_f32_16x16x32_bf16(pa, fvl, oacc[dt], 0, 0, 0);
            }
        }
    }

    // normalize + store fp32 to [B,S,A]
    #pragma unroll
    for (int r = 0; r < 4; ++r) {
        float inv = 1.0f / l_r[r];
        int row = qt * 64 + wave * 16 + lg * 4 + r;
        size_t obase = ((size_t)b * S_N + row) * D_N + h * HD_N;
        #pragma unroll
        for (int dt = 0; dt < 4; ++dt)
            O[obase + dt * 16 + l15] = oacc[dt][r] * inv;
    }
}

// ---------------------------------------------------------------------------
// Kernel 4: output projection  C = O @ Wo + bo  (fp32 core, unchanged)
// ---------------------------------------------------------------------------
__global__ __launch_bounds__(256)
void out_gemm_kernel(const float* __restrict__ A, const float* __restrict__ Bw,
                     const float* __restrict__ bias, float* __restrict__ C)
{
    const int mt = blockIdx.x;
    const int nt = blockIdx.y;

    __shared__ float As[64][32];
    __shared__ float Bs[32][64];

    const int tid = threadIdx.x;
    const int tx  = tid & 15;
    const int ty  = tid >> 4;
    const int m0  = mt * 64;
    const int n0  = nt * 64;

    const int ar = tid >> 3;
    const int ac = (tid & 7) * 4;
    const int br = tid >> 4;
    const int bc = (tid & 15) * 4;

    float acc[4][4] = {{0.f}};

    for (int k0 = 0; k0 < D_N; k0 += 32) {
        float4 a0 = *(const float4*)&A[(size_t)(m0 + ar) * D_N + k0 + ac];
        float4 a1 = *(const float4*)&A[(size_t)(m0 + 32 + ar) * D_N + k0 + ac];
        float4 b0 = *(const float4*)&Bw[(size_t)(k0 + br) * D_N + n0 + bc];
        float4 b1 = *(const float4*)&Bw[(size_t)(k0 + 16 + br) * D_N + n0 + bc];
        __syncthreads();
        *(float4*)&As[ar][ac]      = a0;
        *(float4*)&As[32 + ar][ac] = a1;
        *(float4*)&Bs[br][bc]      = b0;
        *(float4*)&Bs[16 + br][bc] = b1;
        __syncthreads();
        #pragma unroll
        for (int g = 0; g < 8; ++g) {
            float4 a4[4];
            #pragma unroll
            for (int i = 0; i < 4; ++i)
                a4[i] = *(const float4*)&As[ty * 4 + i][g * 4];
            #pragma unroll
            for (int j = 0; j < 4; ++j) {
                float4 b4 = *(const float4*)&Bs[g * 4 + j][tx * 4];
                #pragma unroll
                for (int i = 0; i < 4; ++i) {
                    float a = (j == 0) ? a4[i].x : (j == 1) ? a4[i].y
                            : (j == 2) ? a4[i].z : a4[i].w;
                    acc[i][0] = fmaf(a, b4.x, acc[i][0]);
                    acc[i][1] = fmaf(a, b4.y, acc[i][1]);
                    acc[i][2] = fmaf(a, b4.z, acc[i][2]);
                    acc[i][3] = fmaf(a, b4.w, acc[i][3]);
                }
            }
        }
    }

    const float4 bias4 = *(const float4*)&bias[n0 + tx * 4];
    #pragma unroll
    for (int i = 0; i < 4; ++i) {
        int m = m0 + ty * 4 + i;
        *(float4*)&C[(size_t)m * D_N + n0 + tx * 4] =
            make_float4(acc[i][0] + bias4.x, acc[i][1] + bias4.y,
                        acc[i][2] + bias4.z, acc[i][3] + bias4.w);
    }
}

// ---------------------------------------------------------------------------
extern "C" void kernel_launch(void* const* d_in, const int* in_sizes, int n_in,
                              void* d_out, int out_size, void* d_ws, size_t ws_size,
                              hipStream_t stream) {
    const float* x  = (const float*)d_in[0];
    const float* Wq = (const float*)d_in[1];
    const float* bq = (const float*)d_in[2];
    const float* Wk = (const float*)d_in[3];
    const float* bk = (const float*)d_in[4];
    const float* Wv = (const float*)d_in[5];
    const float* bv = (const float*)d_in[6];
    const float* Wo = (const float*)d_in[7];
    const float* bo = (const float*)d_in[8];
    float* out = (float*)d_out;

    const size_t NE = (size_t)B_N * H_N * S_N * HD_N;   // 8388608 elements per matrix

    float* cos_t = (float*)d_ws;                        // 65536 f32
    float* sin_t = cos_t + (size_t)S_N * 32;            // 65536 f32
    unsigned short* Qh  = (unsigned short*)(sin_t + (size_t)S_N * 32);
    unsigned short* Ql  = Qh  + NE;
    unsigned short* Kh  = Ql  + NE;
    unsigned short* Kl  = Kh  + NE;
    unsigned short* Vth = Kl  + NE;
    unsigned short* Vtl = Vth + NE;
    float* Obuf = (float*)(Vtl + NE);                   // 8388608 f32

    rope_table_kernel<<<256, 256, 0, stream>>>(cos_t, sin_t);

    dim3 g1(M_N / 64, 48);
    qkv_gemm_kernel<<<g1, 256, 0, stream>>>(x, Wq, bq, Wk, bk, Wv, bv,
                                            cos_t, sin_t,
                                            Qh, Ql, Kh, Kl, Vth, Vtl);

    dim3 g2(S_N / 64, H_N, B_N);
    attn_kernel<<<g2, 256, 0, stream>>>(Qh, Ql, Kh, Kl, Vth, Vtl, Obuf);

    dim3 g3(M_N / 64, 16);
    out_gemm_kernel<<<g3, 256, 0, stream>>>(Obuf, Wo, bo, out);
}

// Round 6
// 661.595 us; speedup vs baseline: 3.5664x; 2.3774x over previous
//
#include <hip/hip_runtime.h>
#include <math.h>

// Problem constants (hard-coded from setup_inputs)
#define B_N 4
#define S_N 2048
#define D_N 1024
#define H_N 16
#define HD_N 64
#define M_N (B_N * S_N)   // 8192

typedef __attribute__((ext_vector_type(8))) short bf16x8;   // 8 bf16 = 4 VGPRs (MFMA A/B frag)
typedef __attribute__((ext_vector_type(4))) float f32x4;    // MFMA C/D frag

// bf16 round-to-nearest-even split helpers
static __device__ __forceinline__ unsigned short f2bf(float f) {
    unsigned int u = __float_as_uint(f);
    u += 0x7FFF + ((u >> 16) & 1);
    return (unsigned short)(u >> 16);
}
static __device__ __forceinline__ float bf2f(unsigned short h) {
    return __uint_as_float(((unsigned int)h) << 16);
}

// ---------------------------------------------------------------------------
// Kernel 1: RoPE cos/sin table (S_N x 32)
// ---------------------------------------------------------------------------
__global__ __launch_bounds__(256)
void rope_table_kernel(float* __restrict__ cos_t, float* __restrict__ sin_t) {
    int idx = blockIdx.x * 256 + threadIdx.x;
    if (idx >= S_N * 32) return;
    int sp = idx >> 5;
    int p  = idx & 31;
    float inv = powf(10000.0f, -(float)p / 32.0f);
    float ang = (float)sp * inv;
    float s, c;
    sincosf(ang, &s, &c);
    cos_t[idx] = c;
    sin_t[idx] = s;
}

// ---------------------------------------------------------------------------
// Kernel 2: weight transpose-split.  W[mat] (1024x1024 f32, [k][n]) ->
// WTh/WTl bf16 [4096][1024] with row = mat*1024 + n, col = k.
// grid (16,16,4), 256 threads. LDS 64x65 f32 tile (padded, conflict-free).
// ---------------------------------------------------------------------------
__global__ __launch_bounds__(256)
void splitT_w_kernel(const float* __restrict__ W0, const float* __restrict__ W1,
                     const float* __restrict__ W2, const float* __restrict__ W3,
                     unsigned short* __restrict__ WTh, unsigned short* __restrict__ WTl)
{
    __shared__ float tile[64][65];
    const int k0  = blockIdx.x * 64;
    const int n0  = blockIdx.y * 64;
    const int mat = blockIdx.z;
    const float* __restrict__ W = (mat == 0) ? W0 : (mat == 1) ? W1 : (mat == 2) ? W2 : W3;
    const int t = threadIdx.x;

    #pragma unroll
    for (int p = 0; p < 4; ++p) {
        int idx = t + p * 256;
        int r = idx >> 4, c4 = (idx & 15) * 4;
        float4 v = *(const float4*)&W[(size_t)(k0 + r) * D_N + n0 + c4];
        tile[r][c4]     = v.x;
        tile[r][c4 + 1] = v.y;
        tile[r][c4 + 2] = v.z;
        tile[r][c4 + 3] = v.w;
    }
    __syncthreads();
    #pragma unroll
    for (int p = 0; p < 4; ++p) {
        int idx = t + p * 256;
        int nl = idx >> 4, kc = (idx & 15) * 4;
        ushort4 hi, lo;
        float f0 = tile[kc][nl], f1 = tile[kc + 1][nl];
        float f2 = tile[kc + 2][nl], f3 = tile[kc + 3][nl];
        hi.x = f2bf(f0); lo.x = f2bf(f0 - bf2f(hi.x));
        hi.y = f2bf(f1); lo.y = f2bf(f1 - bf2f(hi.y));
        hi.z = f2bf(f2); lo.z = f2bf(f2 - bf2f(hi.z));
        hi.w = f2bf(f3); lo.w = f2bf(f3 - bf2f(hi.w));
        size_t base = ((size_t)(mat * D_N + n0 + nl)) * D_N + k0 + kc;
        *(ushort4*)&WTh[base] = hi;
        *(ushort4*)&WTl[base] = lo;
    }
}

// ---------------------------------------------------------------------------
// Shared MFMA GEMM core: 128x128 C-tile, BK=32, 4 waves (2x2), split-bf16
// 3-term (Ah*Bh + Al*Bh + Ah*Bl).  A is fp32 [M][1024] (split during staging);
// B is pre-split bf16 rows [n][1024] (WT layout).
// LDS tiles [128][72] ushort (144B rows: staging writes and frag reads <=2-way).
//   slots 0-3 = hi k-chunks, 4-7 = lo k-chunks (8 bf16 each).
// ---------------------------------------------------------------------------
__device__ __forceinline__ void gemm_core_f32A(
    const float* __restrict__ A,
    const unsigned short* __restrict__ Bh, const unsigned short* __restrict__ Bl,
    int aRow0, int bRow0,
    unsigned short* ldsA, unsigned short* ldsB,
    f32x4 acc[4][4])
{
    const int tid  = threadIdx.x;
    const int wave = tid >> 6;
    const int lane = tid & 63;
    const int l15  = lane & 15;
    const int lg   = lane >> 4;
    const int wr   = wave >> 1;
    const int wc   = wave & 1;

    // A staging: 512 fp32 8-elem chunks (row=c>>2, kc=c&3), 2 per thread
    const float* ga[2];
    int la[2];
    #pragma unroll
    for (int p = 0; p < 2; ++p) {
        int c = tid + p * 256;
        int row = c >> 2, kc = c & 3;
        ga[p] = A + (size_t)(aRow0 + row) * D_N + kc * 8;
        la[p] = row * 72 + kc * 8;
    }
    // B staging: 1024 bf16 8-elem chunks (row=c>>3, srcslot=c&7), 4 per thread
    const unsigned short* gb[4];
    int lb[4];
    #pragma unroll
    for (int p = 0; p < 4; ++p) {
        int c = tid + p * 256;
        int row = c >> 3, ss = c & 7, sel = ss >> 2, kc = ss & 3;
        gb[p] = (sel ? Bl : Bh) + (size_t)(bRow0 + row) * D_N + kc * 8;
        lb[p] = row * 72 + ss * 8;
    }

    for (int kk = 0; kk < D_N / 32; ++kk) {
        // global loads for this tile
        float4 av[2][2];
        bf16x8 bv[4];
        #pragma unroll
        for (int p = 0; p < 2; ++p) {
            av[p][0] = *(const float4*)ga[p];
            av[p][1] = *(const float4*)(ga[p] + 4);
            ga[p] += 32;
        }
        #pragma unroll
        for (int p = 0; p < 4; ++p) {
            bv[p] = *(const bf16x8*)gb[p];
            gb[p] += 32;
        }
        __syncthreads();   // previous tile fully consumed
        #pragma unroll
        for (int p = 0; p < 2; ++p) {
            bf16x8 hi, lo;
            float v[8] = {av[p][0].x, av[p][0].y, av[p][0].z, av[p][0].w,
                          av[p][1].x, av[p][1].y, av[p][1].z, av[p][1].w};
            #pragma unroll
            for (int q = 0; q < 8; ++q) {
                unsigned short h = f2bf(v[q]);
                hi[q] = (short)h;
                lo[q] = (short)f2bf(v[q] - bf2f(h));
            }
            *(bf16x8*)&ldsA[la[p]]      = hi;
            *(bf16x8*)&ldsA[la[p] + 32] = lo;
        }
        #pragma unroll
        for (int p = 0; p < 4; ++p)
            *(bf16x8*)&ldsB[lb[p]] = bv[p];
        __syncthreads();

        // fragment loads (all <=2-way bank aliased thanks to 144B row pitch)
        bf16x8 ah[4], al[4], bh[4], bl[4];
        #pragma unroll
        for (int i = 0; i < 4; ++i) {
            int ar = wr * 64 + i * 16 + l15;
            ah[i] = *(const bf16x8*)&ldsA[ar * 72 + lg * 8];
            al[i] = *(const bf16x8*)&ldsA[ar * 72 + 32 + lg * 8];
            int br = wc * 64 + i * 16 + l15;
            bh[i] = *(const bf16x8*)&ldsB[br * 72 + lg * 8];
            bl[i] = *(const bf16x8*)&ldsB[br * 72 + 32 + lg * 8];
        }
        #pragma unroll
        for (int i = 0; i < 4; ++i)
            #pragma unroll
            for (int j = 0; j < 4; ++j) {
                acc[i][j] = __builtin_amdgcn_mfma_f32_16x16x32_bf16(ah[i], bh[j], acc[i][j], 0, 0, 0);
                acc[i][j] = __builtin_amdgcn_mfma_f32_16x16x32_bf16(al[i], bh[j], acc[i][j], 0, 0, 0);
                acc[i][j] = __builtin_amdgcn_mfma_f32_16x16x32_bf16(ah[i], bl[j], acc[i][j], 0, 0, 0);
            }
    }
}

// ---------------------------------------------------------------------------
// Kernel 3: QKV MFMA GEMM + bias + RoPE + hi/lo split-scatter epilogue.
// grid (M/128=64, 3072/128=24). n0 covers mats stacked (Q:0.., K:1024.., V:2048..).
// Outputs (consumed by the unchanged attention kernel):
//   Qh/Ql/Kh/Kl : [B,H,S,64]      Vth/Vtl : [B,H,64,S]
// ---------------------------------------------------------------------------
__global__ __launch_bounds__(256)
void qkv_gemm_kernel(const float* __restrict__ x,
                     const unsigned short* __restrict__ WTh, const unsigned short* __restrict__ WTl,
                     const float* __restrict__ bq, const float* __restrict__ bk,
                     const float* __restrict__ bv_,
                     const float* __restrict__ cos_t, const float* __restrict__ sin_t,
                     unsigned short* __restrict__ Qh, unsigned short* __restrict__ Ql,
                     unsigned short* __restrict__ Kh, unsigned short* __restrict__ Kl,
                     unsigned short* __restrict__ Vth, unsigned short* __restrict__ Vtl)
{
    __shared__ unsigned short ldsA[128 * 72];
    __shared__ unsigned short ldsB[128 * 72];

    const int m0  = blockIdx.x * 128;
    const int n0  = blockIdx.y * 128;   // global col incl. mat offset
    const int mat = n0 >> 10;

    f32x4 acc[4][4];
    #pragma unroll
    for (int i = 0; i < 4; ++i)
        #pragma unroll
        for (int j = 0; j < 4; ++j) acc[i][j] = (f32x4){0.f, 0.f, 0.f, 0.f};

    gemm_core_f32A(x, WTh, WTl, m0, n0, ldsA, ldsB, acc);

    const int tid  = threadIdx.x;
    const int wave = tid >> 6;
    const int lane = tid & 63;
    const int l15  = lane & 15;
    const int lg   = lane >> 4;
    const int wr   = wave >> 1;
    const int wc   = wave & 1;

    const float* __restrict__ bias = (mat == 0) ? bq : (mat == 1) ? bk : bv_;
    unsigned short* __restrict__ Hi = (mat == 0) ? Qh : Kh;
    unsigned short* __restrict__ Lo = (mat == 0) ? Ql : Kl;

    #pragma unroll
    for (int i = 0; i < 4; ++i) {
        #pragma unroll
        for (int j = 0; j < 4; ++j) {
            const int nl   = (n0 & 1023) + wc * 64 + j * 16 + l15;  // col within mat
            const int head = nl >> 6;
            const int d    = nl & 63;
            const float bval = bias[nl];
            const int m_base = m0 + wr * 64 + i * 16 + lg * 4;
            const int bb  = m_base >> 11;
            const int sp0 = m_base & (S_N - 1);

            if (mat == 2) {
                ushort4 hi4, lo4;
                float v0 = acc[i][j][0] + bval;
                float v1 = acc[i][j][1] + bval;
                float v2 = acc[i][j][2] + bval;
                float v3 = acc[i][j][3] + bval;
                hi4.x = f2bf(v0); lo4.x = f2bf(v0 - bf2f(hi4.x));
                hi4.y = f2bf(v1); lo4.y = f2bf(v1 - bf2f(hi4.y));
                hi4.z = f2bf(v2); lo4.z = f2bf(v2 - bf2f(hi4.z));
                hi4.w = f2bf(v3); lo4.w = f2bf(v3 - bf2f(hi4.w));
                size_t base = ((size_t)((bb * H_N + head) * HD_N + d)) * S_N + sp0;
                *(ushort4*)&Vth[base] = hi4;
                *(ushort4*)&Vtl[base] = lo4;
            } else {
                const int p = d >> 1;
                const float sgn = (d & 1) ? 1.0f : -1.0f;
                #pragma unroll
                for (int r = 0; r < 4; ++r) {
                    int sp = sp0 + r;
                    float v = acc[i][j][r] + bval;
                    float part = __shfl_xor(v, 1);   // partner column (d^1)
                    float c = cos_t[sp * 32 + p];
                    float s = sin_t[sp * 32 + p];
                    float vp = v * c + part * s * sgn;
                    if (mat == 0) vp *= 0.125f;      // fold 1/sqrt(64)
                    unsigned short hi = f2bf(vp);
                    unsigned short lo = f2bf(vp - bf2f(hi));
                    size_t base = ((size_t)((bb * H_N + head) * S_N + sp)) * HD_N + d;
                    Hi[base] = hi;
                    Lo[base] = lo;
                }
            }
        }
    }
}

// ---------------------------------------------------------------------------
// Kernel 4: flash attention via split-bf16 MFMA — UNCHANGED (validated r5).
// ---------------------------------------------------------------------------
__global__ __launch_bounds__(256)
void attn_kernel(const unsigned short* __restrict__ Qh, const unsigned short* __restrict__ Ql,
                 const unsigned short* __restrict__ Kh, const unsigned short* __restrict__ Kl,
                 const unsigned short* __restrict__ Vh, const unsigned short* __restrict__ Vl,
                 float* __restrict__ O)
{
    __shared__ __align__(16) unsigned short KhS[4096];
    __shared__ __align__(16) unsigned short KlS[4096];
    __shared__ __align__(16) unsigned short VhS[4096];
    __shared__ __align__(16) unsigned short VlS[4096];
    __shared__ __align__(16) unsigned short Pb[4][1024];

    const int qt = blockIdx.x;
    const int h  = blockIdx.y;
    const int b  = blockIdx.z;
    const int bh = b * H_N + h;

    const int tid  = threadIdx.x;
    const int wave = tid >> 6;
    const int lane = tid & 63;
    const int l15  = lane & 15;
    const int lg   = lane >> 4;

    const int qrow = qt * 64 + wave * 16 + l15;
    const size_t qbase = ((size_t)bh * S_N + qrow) * HD_N;
    bf16x8 qfh[2], qfl[2];
    qfh[0] = *(const bf16x8*)&Qh[qbase + lg * 8];
    qfh[1] = *(const bf16x8*)&Qh[qbase + 32 + lg * 8];
    qfl[0] = *(const bf16x8*)&Ql[qbase + lg * 8];
    qfl[1] = *(const bf16x8*)&Ql[qbase + 32 + lg * 8];

    f32x4 oacc[4];
    #pragma unroll
    for (int dt = 0; dt < 4; ++dt) oacc[dt] = (f32x4){0.f, 0.f, 0.f, 0.f};
    float m_r[4], l_r[4];
    #pragma unroll
    for (int r = 0; r < 4; ++r) { m_r[r] = -1e30f; l_r[r] = 0.f; }

    for (int kt = 0; kt < S_N / 64; ++kt) {
        __syncthreads();
        #pragma unroll
        for (int t = 0; t < 2; ++t) {
            int c   = tid + t * 256;
            int row = c >> 3;
            int sl  = c & 7;
            int li  = (row * 64 + sl * 8) ^ ((row & 7) << 3);
            size_t gk = ((size_t)bh * S_N + kt * 64 + row) * HD_N + sl * 8;
            size_t gv = ((size_t)bh * HD_N + row) * S_N + kt * 64 + sl * 8;
            bf16x8 vkh = *(const bf16x8*)&Kh[gk];
            bf16x8 vkl = *(const bf16x8*)&Kl[gk];
            bf16x8 vvh = *(const bf16x8*)&Vh[gv];
            bf16x8 vvl = *(const bf16x8*)&Vl[gv];
            *(bf16x8*)&KhS[li] = vkh;
            *(bf16x8*)&KlS[li] = vkl;
            *(bf16x8*)&VhS[li] = vvh;
            *(bf16x8*)&VlS[li] = vvl;
        }
        __syncthreads();

        f32x4 s[4];
        #pragma unroll
        for (int nt = 0; nt < 4; ++nt) s[nt] = (f32x4){0.f, 0.f, 0.f, 0.f};
        #pragma unroll
        for (int ks = 0; ks < 2; ++ks) {
            #pragma unroll
            for (int nt = 0; nt < 4; ++nt) {
                int row = nt * 16 + l15;
                int bi  = (row * 64 + ks * 32 + lg * 8) ^ ((row & 7) << 3);
                bf16x8 fkh = *(const bf16x8*)&KhS[bi];
                bf16x8 fkl = *(const bf16x8*)&KlS[bi];
                s[nt] = __builtin_amdgcn_mfma_f32_16x16x32_bf16(qfh[ks], fkh, s[nt], 0, 0, 0);
                s[nt] = __builtin_amdgcn_mfma_f32_16x16x32_bf16(qfl[ks], fkh, s[nt], 0, 0, 0);
                s[nt] = __builtin_amdgcn_mfma_f32_16x16x32_bf16(qfh[ks], fkl, s[nt], 0, 0, 0);
            }
        }

        #pragma unroll
        for (int r = 0; r < 4; ++r) {
            float mx = fmaxf(fmaxf(s[0][r], s[1][r]), fmaxf(s[2][r], s[3][r]));
            mx = fmaxf(mx, __shfl_xor(mx, 1));
            mx = fmaxf(mx, __shfl_xor(mx, 2));
            mx = fmaxf(mx, __shfl_xor(mx, 4));
            mx = fmaxf(mx, __shfl_xor(mx, 8));
            float mnew = fmaxf(m_r[r], mx);
            float al   = __expf(m_r[r] - mnew);
            float ps   = 0.f;
            #pragma unroll
            for (int nt = 0; nt < 4; ++nt) {
                float p = __expf(s[nt][r] - mnew);
                s[nt][r] = p;
                ps += p;
            }
            ps += __shfl_xor(ps, 1);
            ps += __shfl_xor(ps, 2);
            ps += __shfl_xor(ps, 4);
            ps += __shfl_xor(ps, 8);
            l_r[r] = l_r[r] * al + ps;
            m_r[r] = mnew;
            oacc[0][r] *= al; oacc[1][r] *= al;
            oacc[2][r] *= al; oacc[3][r] *= al;
            int prow = lg * 4 + r;
            #pragma unroll
            for (int nt = 0; nt < 4; ++nt) {
                Pb[wave][(prow * 64 + nt * 16 + l15) ^ ((prow & 7) << 3)] = f2bf(s[nt][r]);
            }
        }
        asm volatile("s_waitcnt lgkmcnt(0)" ::: "memory");

        #pragma unroll
        for (int ks = 0; ks < 2; ++ks) {
            int pi = (l15 * 64 + ks * 32 + lg * 8) ^ ((l15 & 7) << 3);
            bf16x8 pa = *(const bf16x8*)&Pb[wave][pi];
            #pragma unroll
            for (int dt = 0; dt < 4; ++dt) {
                int vrow = dt * 16 + l15;
                int vbi  = (vrow * 64 + ks * 32 + lg * 8) ^ ((vrow & 7) << 3);
                bf16x8 fvh = *(const bf16x8*)&VhS[vbi];
                bf16x8 fvl = *(const bf16x8*)&VlS[vbi];
                oacc[dt] = __builtin_amdgcn_mfma_f32_16x16x32_bf16(pa, fvh, oacc[dt], 0, 0, 0);
                oacc[dt] = __builtin_amdgcn_mfma_f32_16x16x32_bf16(pa, fvl, oacc[dt], 0, 0, 0);
            }
        }
    }

    #pragma unroll
    for (int r = 0; r < 4; ++r) {
        float inv = 1.0f / l_r[r];
        int row = qt * 64 + wave * 16 + lg * 4 + r;
        size_t obase = ((size_t)b * S_N + row) * D_N + h * HD_N;
        #pragma unroll
        for (int dt = 0; dt < 4; ++dt)
            O[obase + dt * 16 + l15] = oacc[dt][r] * inv;
    }
}

// ---------------------------------------------------------------------------
// Kernel 5: output projection via split-bf16 MFMA.  A = Obuf fp32 (staging-
// split), B = WoT rows 3072.., epilogue bias + fp32 store.  grid (64, 8).
// ---------------------------------------------------------------------------
__global__ __launch_bounds__(256)
void out_gemm_kernel(const float* __restrict__ A,
                     const unsigned short* __restrict__ WTh, const unsigned short* __restrict__ WTl,
                     const float* __restrict__ bo, float* __restrict__ out)
{
    __shared__ unsigned short ldsA[128 * 72];
    __shared__ unsigned short ldsB[128 * 72];

    const int m0 = blockIdx.x * 128;
    const int n0 = blockIdx.y * 128;

    f32x4 acc[4][4];
    #pragma unroll
    for (int i = 0; i < 4; ++i)
        #pragma unroll
        for (int j = 0; j < 4; ++j) acc[i][j] = (f32x4){0.f, 0.f, 0.f, 0.f};

    gemm_core_f32A(A, WTh, WTl, m0, 3 * D_N + n0, ldsA, ldsB, acc);

    const int tid  = threadIdx.x;
    const int wave = tid >> 6;
    const int lane = tid & 63;
    const int l15  = lane & 15;
    const int lg   = lane >> 4;
    const int wr   = wave >> 1;
    const int wc   = wave & 1;

    #pragma unroll
    for (int i = 0; i < 4; ++i) {
        #pragma unroll
        for (int j = 0; j < 4; ++j) {
            int n = n0 + wc * 64 + j * 16 + l15;
            float bval = bo[n];
            int m_base = m0 + wr * 64 + i * 16 + lg * 4;
            #pragma unroll
            for (int r = 0; r < 4; ++r)
                out[(size_t)(m_base + r) * D_N + n] = acc[i][j][r] + bval;
        }
    }
}

// ---------------------------------------------------------------------------
extern "C" void kernel_launch(void* const* d_in, const int* in_sizes, int n_in,
                              void* d_out, int out_size, void* d_ws, size_t ws_size,
                              hipStream_t stream) {
    const float* x  = (const float*)d_in[0];
    const float* Wq = (const float*)d_in[1];
    const float* bq = (const float*)d_in[2];
    const float* Wk = (const float*)d_in[3];
    const float* bk = (const float*)d_in[4];
    const float* Wv = (const float*)d_in[5];
    const float* bv = (const float*)d_in[6];
    const float* Wo = (const float*)d_in[7];
    const float* bo = (const float*)d_in[8];
    float* out = (float*)d_out;

    const size_t NE = (size_t)B_N * H_N * S_N * HD_N;   // 8388608 per split matrix
    const size_t WTE = (size_t)4 * D_N * D_N;           // 4194304

    float* cos_t = (float*)d_ws;                        // 65536 f32
    float* sin_t = cos_t + (size_t)S_N * 32;            // 65536 f32
    unsigned short* WTh = (unsigned short*)(sin_t + (size_t)S_N * 32);
    unsigned short* WTl = WTh + WTE;
    unsigned short* Qh  = WTl + WTE;
    unsigned short* Ql  = Qh  + NE;
    unsigned short* Kh  = Ql  + NE;
    unsigned short* Kl  = Kh  + NE;
    unsigned short* Vth = Kl  + NE;
    unsigned short* Vtl = Vth + NE;
    float* Obuf = (float*)(Vtl + NE);                   // 8388608 f32
    // total ws: 0.5 + 16 + 96 + 32 = 144.5 MB

    rope_table_kernel<<<256, 256, 0, stream>>>(cos_t, sin_t);

    dim3 gw(16, 16, 4);
    splitT_w_kernel<<<gw, 256, 0, stream>>>(Wq, Wk, Wv, Wo, WTh, WTl);

    dim3 g1(M_N / 128, 24);
    qkv_gemm_kernel<<<g1, 256, 0, stream>>>(x, WTh, WTl, bq, bk, bv,
                                            cos_t, sin_t,
                                            Qh, Ql, Kh, Kl, Vth, Vtl);

    dim3 g2(S_N / 64, H_N, B_N);
    attn_kernel<<<g2, 256, 0, stream>>>(Qh, Ql, Kh, Kl, Vth, Vtl, Obuf);

    dim3 g3(M_N / 128, 8);
    out_gemm_kernel<<<g3, 256, 0, stream>>>(Obuf, WTh, WTl, bo, out);
}

// Round 10
// 608.118 us; speedup vs baseline: 3.8801x; 1.0879x over previous
//
#include <hip/hip_runtime.h>
#include <math.h>

// Problem constants (hard-coded from setup_inputs)
#define B_N 4
#define S_N 2048
#define D_N 1024
#define H_N 16
#define HD_N 64
#define M_N (B_N * S_N)   // 8192

typedef __attribute__((ext_vector_type(8))) short bf16x8;   // 8 bf16 = 4 VGPRs (MFMA A/B frag)
typedef __attribute__((ext_vector_type(4))) float f32x4;    // MFMA C/D frag

// bf16 round-to-nearest-even split helpers
static __device__ __forceinline__ unsigned short f2bf(float f) {
    unsigned int u = __float_as_uint(f);
    u += 0x7FFF + ((u >> 16) & 1);
    return (unsigned short)(u >> 16);
}
static __device__ __forceinline__ float bf2f(unsigned short h) {
    return __uint_as_float(((unsigned int)h) << 16);
}

// ---------------------------------------------------------------------------
// Kernel 1: RoPE cos/sin table (S_N x 32)
// ---------------------------------------------------------------------------
__global__ __launch_bounds__(256)
void rope_table_kernel(float* __restrict__ cos_t, float* __restrict__ sin_t) {
    int idx = blockIdx.x * 256 + threadIdx.x;
    if (idx >= S_N * 32) return;
    int sp = idx >> 5;
    int p  = idx & 31;
    float inv = powf(10000.0f, -(float)p / 32.0f);
    float ang = (float)sp * inv;
    float s, c;
    sincosf(ang, &s, &c);
    cos_t[idx] = c;
    sin_t[idx] = s;
}

// ---------------------------------------------------------------------------
// Kernel 2: weight transpose-split.  W[mat] (1024x1024 f32, [k][n]) ->
// WTh/WTl bf16 [4096][1024] with row = mat*1024 + n, col = k.
// ---------------------------------------------------------------------------
__global__ __launch_bounds__(256)
void splitT_w_kernel(const float* __restrict__ W0, const float* __restrict__ W1,
                     const float* __restrict__ W2, const float* __restrict__ W3,
                     unsigned short* __restrict__ WTh, unsigned short* __restrict__ WTl)
{
    __shared__ float tile[64][65];
    const int k0  = blockIdx.x * 64;
    const int n0  = blockIdx.y * 64;
    const int mat = blockIdx.z;
    const float* __restrict__ W = (mat == 0) ? W0 : (mat == 1) ? W1 : (mat == 2) ? W2 : W3;
    const int t = threadIdx.x;

    #pragma unroll
    for (int p = 0; p < 4; ++p) {
        int idx = t + p * 256;
        int r = idx >> 4, c4 = (idx & 15) * 4;
        float4 v = *(const float4*)&W[(size_t)(k0 + r) * D_N + n0 + c4];
        tile[r][c4]     = v.x;
        tile[r][c4 + 1] = v.y;
        tile[r][c4 + 2] = v.z;
        tile[r][c4 + 3] = v.w;
    }
    __syncthreads();
    #pragma unroll
    for (int p = 0; p < 4; ++p) {
        int idx = t + p * 256;
        int nl = idx >> 4, kc = (idx & 15) * 4;
        ushort4 hi, lo;
        float f0 = tile[kc][nl], f1 = tile[kc + 1][nl];
        float f2 = tile[kc + 2][nl], f3 = tile[kc + 3][nl];
        hi.x = f2bf(f0); lo.x = f2bf(f0 - bf2f(hi.x));
        hi.y = f2bf(f1); lo.y = f2bf(f1 - bf2f(hi.y));
        hi.z = f2bf(f2); lo.z = f2bf(f2 - bf2f(hi.z));
        hi.w = f2bf(f3); lo.w = f2bf(f3 - bf2f(hi.w));
        size_t base = ((size_t)(mat * D_N + n0 + nl)) * D_N + k0 + kc;
        *(ushort4*)&WTh[base] = hi;
        *(ushort4*)&WTl[base] = lo;
    }
}

// ---------------------------------------------------------------------------
// Shared MFMA GEMM core: 128x128 C-tile, BK=32, 4 waves (2x2), split-bf16
// 3-term (Ah*Bh + Al*Bh + Ah*Bl).  Unchanged from validated round 6.
// ---------------------------------------------------------------------------
__device__ __forceinline__ void gemm_core_f32A(
    const float* __restrict__ A,
    const unsigned short* __restrict__ Bh, const unsigned short* __restrict__ Bl,
    int aRow0, int bRow0,
    unsigned short* ldsA, unsigned short* ldsB,
    f32x4 acc[4][4])
{
    const int tid  = threadIdx.x;
    const int wave = tid >> 6;
    const int lane = tid & 63;
    const int l15  = lane & 15;
    const int lg   = lane >> 4;
    const int wr   = wave >> 1;
    const int wc   = wave & 1;

    const float* ga[2];
    int la[2];
    #pragma unroll
    for (int p = 0; p < 2; ++p) {
        int c = tid + p * 256;
        int row = c >> 2, kc = c & 3;
        ga[p] = A + (size_t)(aRow0 + row) * D_N + kc * 8;
        la[p] = row * 72 + kc * 8;
    }
    const unsigned short* gb[4];
    int lb[4];
    #pragma unroll
    for (int p = 0; p < 4; ++p) {
        int c = tid + p * 256;
        int row = c >> 3, ss = c & 7, sel = ss >> 2, kc = ss & 3;
        gb[p] = (sel ? Bl : Bh) + (size_t)(bRow0 + row) * D_N + kc * 8;
        lb[p] = row * 72 + ss * 8;
    }

    for (int kk = 0; kk < D_N / 32; ++kk) {
        float4 av[2][2];
        bf16x8 bv[4];
        #pragma unroll
        for (int p = 0; p < 2; ++p) {
            av[p][0] = *(const float4*)ga[p];
            av[p][1] = *(const float4*)(ga[p] + 4);
            ga[p] += 32;
        }
        #pragma unroll
        for (int p = 0; p < 4; ++p) {
            bv[p] = *(const bf16x8*)gb[p];
            gb[p] += 32;
        }
        __syncthreads();
        #pragma unroll
        for (int p = 0; p < 2; ++p) {
            bf16x8 hi, lo;
            float v[8] = {av[p][0].x, av[p][0].y, av[p][0].z, av[p][0].w,
                          av[p][1].x, av[p][1].y, av[p][1].z, av[p][1].w};
            #pragma unroll
            for (int q = 0; q < 8; ++q) {
                unsigned short h = f2bf(v[q]);
                hi[q] = (short)h;
                lo[q] = (short)f2bf(v[q] - bf2f(h));
            }
            *(bf16x8*)&ldsA[la[p]]      = hi;
            *(bf16x8*)&ldsA[la[p] + 32] = lo;
        }
        #pragma unroll
        for (int p = 0; p < 4; ++p)
            *(bf16x8*)&ldsB[lb[p]] = bv[p];
        __syncthreads();

        bf16x8 ah[4], al[4], bh[4], bl[4];
        #pragma unroll
        for (int i = 0; i < 4; ++i) {
            int ar = wr * 64 + i * 16 + l15;
            ah[i] = *(const bf16x8*)&ldsA[ar * 72 + lg * 8];
            al[i] = *(const bf16x8*)&ldsA[ar * 72 + 32 + lg * 8];
            int br = wc * 64 + i * 16 + l15;
            bh[i] = *(const bf16x8*)&ldsB[br * 72 + lg * 8];
            bl[i] = *(const bf16x8*)&ldsB[br * 72 + 32 + lg * 8];
        }
        #pragma unroll
        for (int i = 0; i < 4; ++i)
            #pragma unroll
            for (int j = 0; j < 4; ++j) {
                acc[i][j] = __builtin_amdgcn_mfma_f32_16x16x32_bf16(ah[i], bh[j], acc[i][j], 0, 0, 0);
                acc[i][j] = __builtin_amdgcn_mfma_f32_16x16x32_bf16(al[i], bh[j], acc[i][j], 0, 0, 0);
                acc[i][j] = __builtin_amdgcn_mfma_f32_16x16x32_bf16(ah[i], bl[j], acc[i][j], 0, 0, 0);
            }
    }
}

// ---------------------------------------------------------------------------
// Kernel 3: QKV MFMA GEMM + bias + RoPE + hi/lo split-scatter epilogue.
// Unchanged from validated round 6.
// ---------------------------------------------------------------------------
__global__ __launch_bounds__(256)
void qkv_gemm_kernel(const float* __restrict__ x,
                     const unsigned short* __restrict__ WTh, const unsigned short* __restrict__ WTl,
                     const float* __restrict__ bq, const float* __restrict__ bk,
                     const float* __restrict__ bv_,
                     const float* __restrict__ cos_t, const float* __restrict__ sin_t,
                     unsigned short* __restrict__ Qh, unsigned short* __restrict__ Ql,
                     unsigned short* __restrict__ Kh, unsigned short* __restrict__ Kl,
                     unsigned short* __restrict__ Vth, unsigned short* __restrict__ Vtl)
{
    __shared__ unsigned short ldsA[128 * 72];
    __shared__ unsigned short ldsB[128 * 72];

    const int m0  = blockIdx.x * 128;
    const int n0  = blockIdx.y * 128;
    const int mat = n0 >> 10;

    f32x4 acc[4][4];
    #pragma unroll
    for (int i = 0; i < 4; ++i)
        #pragma unroll
        for (int j = 0; j < 4; ++j) acc[i][j] = (f32x4){0.f, 0.f, 0.f, 0.f};

    gemm_core_f32A(x, WTh, WTl, m0, n0, ldsA, ldsB, acc);

    const int tid  = threadIdx.x;
    const int wave = tid >> 6;
    const int lane = tid & 63;
    const int l15  = lane & 15;
    const int lg   = lane >> 4;
    const int wr   = wave >> 1;
    const int wc   = wave & 1;

    const float* __restrict__ bias = (mat == 0) ? bq : (mat == 1) ? bk : bv_;
    unsigned short* __restrict__ Hi = (mat == 0) ? Qh : Kh;
    unsigned short* __restrict__ Lo = (mat == 0) ? Ql : Kl;

    #pragma unroll
    for (int i = 0; i < 4; ++i) {
        #pragma unroll
        for (int j = 0; j < 4; ++j) {
            const int nl   = (n0 & 1023) + wc * 64 + j * 16 + l15;
            const int head = nl >> 6;
            const int d    = nl & 63;
            const float bval = bias[nl];
            const int m_base = m0 + wr * 64 + i * 16 + lg * 4;
            const int bb  = m_base >> 11;
            const int sp0 = m_base & (S_N - 1);

            if (mat == 2) {
                ushort4 hi4, lo4;
                float v0 = acc[i][j][0] + bval;
                float v1 = acc[i][j][1] + bval;
                float v2 = acc[i][j][2] + bval;
                float v3 = acc[i][j][3] + bval;
                hi4.x = f2bf(v0); lo4.x = f2bf(v0 - bf2f(hi4.x));
                hi4.y = f2bf(v1); lo4.y = f2bf(v1 - bf2f(hi4.y));
                hi4.z = f2bf(v2); lo4.z = f2bf(v2 - bf2f(hi4.z));
                hi4.w = f2bf(v3); lo4.w = f2bf(v3 - bf2f(hi4.w));
                size_t base = ((size_t)((bb * H_N + head) * HD_N + d)) * S_N + sp0;
                *(ushort4*)&Vth[base] = hi4;
                *(ushort4*)&Vtl[base] = lo4;
            } else {
                const int p = d >> 1;
                const float sgn = (d & 1) ? 1.0f : -1.0f;
                #pragma unroll
                for (int r = 0; r < 4; ++r) {
                    int sp = sp0 + r;
                    float v = acc[i][j][r] + bval;
                    float part = __shfl_xor(v, 1);
                    float c = cos_t[sp * 32 + p];
                    float s = sin_t[sp * 32 + p];
                    float vp = v * c + part * s * sgn;
                    if (mat == 0) vp *= 0.125f;
                    unsigned short hi = f2bf(vp);
                    unsigned short lo = f2bf(vp - bf2f(hi));
                    size_t base = ((size_t)((bb * H_N + head) * S_N + sp)) * HD_N + d;
                    Hi[base] = hi;
                    Lo[base] = lo;
                }
            }
        }
    }
}

// ---------------------------------------------------------------------------
// Kernel 4: flash attention, split-bf16 MFMA.  32 q-rows per wave
// (QBLK=128/block) so K/V LDS fragment reads are reused across two 16-row
// blocks -> 2x MFMA per LDS byte.  s_setprio(1) around MFMA clusters (T5).
// grid = (S/128, H, B), 256 threads.
// ---------------------------------------------------------------------------
__global__ __launch_bounds__(256)
void attn_kernel(const unsigned short* __restrict__ Qh, const unsigned short* __restrict__ Ql,
                 const unsigned short* __restrict__ Kh, const unsigned short* __restrict__ Kl,
                 const unsigned short* __restrict__ Vh, const unsigned short* __restrict__ Vl,
                 float* __restrict__ O)
{
    __shared__ __align__(16) unsigned short KhS[4096];
    __shared__ __align__(16) unsigned short KlS[4096];
    __shared__ __align__(16) unsigned short VhS[4096];
    __shared__ __align__(16) unsigned short VlS[4096];
    __shared__ __align__(16) unsigned short Pb[4][2048];   // per-wave P tile [32][64]

    const int qt = blockIdx.x;   // 0..15
    const int h  = blockIdx.y;
    const int b  = blockIdx.z;
    const int bh = b * H_N + h;

    const int tid  = threadIdx.x;
    const int wave = tid >> 6;
    const int lane = tid & 63;
    const int l15  = lane & 15;
    const int lg   = lane >> 4;

    // Q fragments for two 16-row blocks (rb=0,1): rows qt*128 + wave*32 + rb*16 + l15
    bf16x8 qfh[2][2], qfl[2][2];
    #pragma unroll
    for (int rb = 0; rb < 2; ++rb) {
        const int qrow = qt * 128 + wave * 32 + rb * 16 + l15;
        const size_t qbase = ((size_t)bh * S_N + qrow) * HD_N;
        qfh[rb][0] = *(const bf16x8*)&Qh[qbase + lg * 8];
        qfh[rb][1] = *(const bf16x8*)&Qh[qbase + 32 + lg * 8];
        qfl[rb][0] = *(const bf16x8*)&Ql[qbase + lg * 8];
        qfl[rb][1] = *(const bf16x8*)&Ql[qbase + 32 + lg * 8];
    }

    f32x4 oacc[2][4];
    float m_r[2][4], l_r[2][4];
    #pragma unroll
    for (int rb = 0; rb < 2; ++rb) {
        #pragma unroll
        for (int dt = 0; dt < 4; ++dt) oacc[rb][dt] = (f32x4){0.f, 0.f, 0.f, 0.f};
        #pragma unroll
        for (int r = 0; r < 4; ++r) { m_r[rb][r] = -1e30f; l_r[rb][r] = 0.f; }
    }

    for (int kt = 0; kt < S_N / 64; ++kt) {
        __syncthreads();   // prior tile's K/V readers done before overwrite
        #pragma unroll
        for (int t = 0; t < 2; ++t) {
            int c   = tid + t * 256;
            int row = c >> 3;
            int sl  = c & 7;
            int li  = (row * 64 + sl * 8) ^ ((row & 7) << 3);
            size_t gk = ((size_t)bh * S_N + kt * 64 + row) * HD_N + sl * 8;
            size_t gv = ((size_t)bh * HD_N + row) * S_N + kt * 64 + sl * 8;
            bf16x8 vkh = *(const bf16x8*)&Kh[gk];
            bf16x8 vkl = *(const bf16x8*)&Kl[gk];
            bf16x8 vvh = *(const bf16x8*)&Vh[gv];
            bf16x8 vvl = *(const bf16x8*)&Vl[gv];
            *(bf16x8*)&KhS[li] = vkh;
            *(bf16x8*)&KlS[li] = vkl;
            *(bf16x8*)&VhS[li] = vvh;
            *(bf16x8*)&VlS[li] = vvl;
        }
        __syncthreads();

        // S = Q K^T, both row-blocks share each K fragment read
        f32x4 s[2][4];
        #pragma unroll
        for (int rb = 0; rb < 2; ++rb)
            #pragma unroll
            for (int nt = 0; nt < 4; ++nt) s[rb][nt] = (f32x4){0.f, 0.f, 0.f, 0.f};
        __builtin_amdgcn_s_setprio(1);
        #pragma unroll
        for (int ks = 0; ks < 2; ++ks) {
            #pragma unroll
            for (int nt = 0; nt < 4; ++nt) {
                int row = nt * 16 + l15;
                int bi  = (row * 64 + ks * 32 + lg * 8) ^ ((row & 7) << 3);
                bf16x8 fkh = *(const bf16x8*)&KhS[bi];
                bf16x8 fkl = *(const bf16x8*)&KlS[bi];
                #pragma unroll
                for (int rb = 0; rb < 2; ++rb) {
                    s[rb][nt] = __builtin_amdgcn_mfma_f32_16x16x32_bf16(qfh[rb][ks], fkh, s[rb][nt], 0, 0, 0);
                    s[rb][nt] = __builtin_amdgcn_mfma_f32_16x16x32_bf16(qfl[rb][ks], fkh, s[rb][nt], 0, 0, 0);
                    s[rb][nt] = __builtin_amdgcn_mfma_f32_16x16x32_bf16(qfh[rb][ks], fkl, s[rb][nt], 0, 0, 0);
                }
            }
        }
        __builtin_amdgcn_s_setprio(0);

        // online softmax per row-block; C layout: row = lg*4+r, col = nt*16+l15
        #pragma unroll
        for (int rb = 0; rb < 2; ++rb) {
            #pragma unroll
            for (int r = 0; r < 4; ++r) {
                float mx = fmaxf(fmaxf(s[rb][0][r], s[rb][1][r]), fmaxf(s[rb][2][r], s[rb][3][r]));
                mx = fmaxf(mx, __shfl_xor(mx, 1));
                mx = fmaxf(mx, __shfl_xor(mx, 2));
                mx = fmaxf(mx, __shfl_xor(mx, 4));
                mx = fmaxf(mx, __shfl_xor(mx, 8));
                float mnew = fmaxf(m_r[rb][r], mx);
                float al   = __expf(m_r[rb][r] - mnew);
                float ps   = 0.f;
                #pragma unroll
                for (int nt = 0; nt < 4; ++nt) {
                    float p = __expf(s[rb][nt][r] - mnew);
                    s[rb][nt][r] = p;
                    ps += p;
                }
                ps += __shfl_xor(ps, 1);
                ps += __shfl_xor(ps, 2);
                ps += __shfl_xor(ps, 4);
                ps += __shfl_xor(ps, 8);
                l_r[rb][r] = l_r[rb][r] * al + ps;
                m_r[rb][r] = mnew;
                oacc[rb][0][r] *= al; oacc[rb][1][r] *= al;
                oacc[rb][2][r] *= al; oacc[rb][3][r] *= al;
                int prow = rb * 16 + lg * 4 + r;
                #pragma unroll
                for (int nt = 0; nt < 4; ++nt) {
                    Pb[wave][(prow * 64 + nt * 16 + l15) ^ ((prow & 7) << 3)] = f2bf(s[rb][nt][r]);
                }
            }
        }
        // wave-private buffer: LDS completion order only, no cross-wave barrier
        asm volatile("s_waitcnt lgkmcnt(0)" ::: "memory");

        // O += P @ V : V fragments shared across both row-blocks
        __builtin_amdgcn_s_setprio(1);
        #pragma unroll
        for (int ks = 0; ks < 2; ++ks) {
            int pr0 = l15;
            int pr1 = 16 + l15;
            bf16x8 pa0 = *(const bf16x8*)&Pb[wave][(pr0 * 64 + ks * 32 + lg * 8) ^ ((pr0 & 7) << 3)];
            bf16x8 pa1 = *(const bf16x8*)&Pb[wave][(pr1 * 64 + ks * 32 + lg * 8) ^ ((pr1 & 7) << 3)];
            #pragma unroll
            for (int dt = 0; dt < 4; ++dt) {
                int vrow = dt * 16 + l15;
                int vbi  = (vrow * 64 + ks * 32 + lg * 8) ^ ((vrow & 7) << 3);
                bf16x8 fvh = *(const bf16x8*)&VhS[vbi];
                bf16x8 fvl = *(const bf16x8*)&VlS[vbi];
                oacc[0][dt] = __builtin_amdgcn_mfma_f32_16x16x32_bf16(pa0, fvh, oacc[0][dt], 0, 0, 0);
                oacc[0][dt] = __builtin_amdgcn_mfma_f32_16x16x32_bf16(pa0, fvl, oacc[0][dt], 0, 0, 0);
                oacc[1][dt] = __builtin_amdgcn_mfma_f32_16x16x32_bf16(pa1, fvh, oacc[1][dt], 0, 0, 0);
                oacc[1][dt] = __builtin_amdgcn_mfma_f32_16x16x32_bf16(pa1, fvl, oacc[1][dt], 0, 0, 0);
            }
        }
        __builtin_amdgcn_s_setprio(0);
    }

    // normalize + store fp32 to [B,S,A]
    #pragma unroll
    for (int rb = 0; rb < 2; ++rb) {
        #pragma unroll
        for (int r = 0; r < 4; ++r) {
            float inv = 1.0f / l_r[rb][r];
            int row = qt * 128 + wave * 32 + rb * 16 + lg * 4 + r;
            size_t obase = ((size_t)b * S_N + row) * D_N + h * HD_N;
            #pragma unroll
            for (int dt = 0; dt < 4; ++dt)
                O[obase + dt * 16 + l15] = oacc[rb][dt][r] * inv;
        }
    }
}

// ---------------------------------------------------------------------------
// Kernel 5: output projection via split-bf16 MFMA.  Unchanged from round 6.
// ---------------------------------------------------------------------------
__global__ __launch_bounds__(256)
void out_gemm_kernel(const float* __restrict__ A,
                     const unsigned short* __restrict__ WTh, const unsigned short* __restrict__ WTl,
                     const float* __restrict__ bo, float* __restrict__ out)
{
    __shared__ unsigned short ldsA[128 * 72];
    __shared__ unsigned short ldsB[128 * 72];

    const int m0 = blockIdx.x * 128;
    const int n0 = blockIdx.y * 128;

    f32x4 acc[4][4];
    #pragma unroll
    for (int i = 0; i < 4; ++i)
        #pragma unroll
        for (int j = 0; j < 4; ++j) acc[i][j] = (f32x4){0.f, 0.f, 0.f, 0.f};

    gemm_core_f32A(A, WTh, WTl, m0, 3 * D_N + n0, ldsA, ldsB, acc);

    const int tid  = threadIdx.x;
    const int wave = tid >> 6;
    const int lane = tid & 63;
    const int l15  = lane & 15;
    const int lg   = lane >> 4;
    const int wr   = wave >> 1;
    const int wc   = wave & 1;

    #pragma unroll
    for (int i = 0; i < 4; ++i) {
        #pragma unroll
        for (int j = 0; j < 4; ++j) {
            int n = n0 + wc * 64 + j * 16 + l15;
            float bval = bo[n];
            int m_base = m0 + wr * 64 + i * 16 + lg * 4;
            #pragma unroll
            for (int r = 0; r < 4; ++r)
                out[(size_t)(m_base + r) * D_N + n] = acc[i][j][r] + bval;
        }
    }
}

// ---------------------------------------------------------------------------
extern "C" void kernel_launch(void* const* d_in, const int* in_sizes, int n_in,
                              void* d_out, int out_size, void* d_ws, size_t ws_size,
                              hipStream_t stream) {
    const float* x  = (const float*)d_in[0];
    const float* Wq = (const float*)d_in[1];
    const float* bq = (const float*)d_in[2];
    const float* Wk = (const float*)d_in[3];
    const float* bk = (const float*)d_in[4];
    const float* Wv = (const float*)d_in[5];
    const float* bv = (const float*)d_in[6];
    const float* Wo = (const float*)d_in[7];
    const float* bo = (const float*)d_in[8];
    float* out = (float*)d_out;

    const size_t NE = (size_t)B_N * H_N * S_N * HD_N;   // 8388608 per split matrix
    const size_t WTE = (size_t)4 * D_N * D_N;           // 4194304

    float* cos_t = (float*)d_ws;
    float* sin_t = cos_t + (size_t)S_N * 32;
    unsigned short* WTh = (unsigned short*)(sin_t + (size_t)S_N * 32);
    unsigned short* WTl = WTh + WTE;
    unsigned short* Qh  = WTl + WTE;
    unsigned short* Ql  = Qh  + NE;
    unsigned short* Kh  = Ql  + NE;
    unsigned short* Kl  = Kh  + NE;
    unsigned short* Vth = Kl  + NE;
    unsigned short* Vtl = Vth + NE;
    float* Obuf = (float*)(Vtl + NE);
    // total ws: 0.5 + 16 + 96 + 32 = 144.5 MB

    rope_table_kernel<<<256, 256, 0, stream>>>(cos_t, sin_t);

    dim3 gw(16, 16, 4);
    splitT_w_kernel<<<gw, 256, 0, stream>>>(Wq, Wk, Wv, Wo, WTh, WTl);

    dim3 g1(M_N / 128, 24);
    qkv_gemm_kernel<<<g1, 256, 0, stream>>>(x, WTh, WTl, bq, bk, bv,
                                            cos_t, sin_t,
                                            Qh, Ql, Kh, Kl, Vth, Vtl);

    dim3 g2(S_N / 128, H_N, B_N);
    attn_kernel<<<g2, 256, 0, stream>>>(Qh, Ql, Kh, Kl, Vth, Vtl, Obuf);

    dim3 g3(M_N / 128, 8);
    out_gemm_kernel<<<g3, 256, 0, stream>>>(Obuf, WTh, WTl, bo, out);
}